// Round 6
// baseline (129.831 us; speedup 1.0000x reference)
//
#include <hip/hip_runtime.h>

#define S_DIM 16
#define B_DIM 512
#define H_DIM 2048
#define EPS 1e-8f

typedef short bf16x8 __attribute__((ext_vector_type(8)));
typedef float f32x4 __attribute__((ext_vector_type(4)));

// Fragment-tile layout (both A and B operands of mfma_f32_16x16x32_bf16):
//   tile (i, ki) covers rows/cols i*16..i*16+15, k = ki*32..ki*32+31.
//   lane l holds elements [row=l&15][k=(l>>4)*8 .. +7]  (16 B, bf16x8).
//   flat short index: (i*(H/32) + ki)*512 + l*8 + j ,  H/32 = 64.
#define KT (H_DIM / 32)   // 64 k-tiles

__device__ __forceinline__ unsigned short f2bf(float f) {
    union { float f; unsigned int u; } v; v.f = f;
    unsigned int u = v.u;
    unsigned int r = (u + 0x7fffu + ((u >> 16) & 1u)) >> 16;
    return (unsigned short)r;
}

__device__ __forceinline__ float dot4(const float4& a, const float4& b) {
    return a.x*b.x + a.y*b.y + a.z*b.z + a.w*b.w;
}

// ---------------- Kernel 1: sims + weighted mean -> wrep_sw, fused W->Wb_sw ----------------
// Same compute structure as R5 (best). Stores now land in fragment-tile order.
__global__ __launch_bounds__(512, 4) void simwrep_kernel(
    const float* __restrict__ OG, const float* __restrict__ E,
    const float* __restrict__ W, unsigned short* __restrict__ wrep_sw,
    unsigned short* __restrict__ Wb_sw) {
    const int b = blockIdx.x;
    const int t = threadIdx.x;
    const int lane = t & 63;
    const int wave = t >> 6;

    __shared__ float4 ogs[512];      // 8 KiB
    __shared__ float4 buf[8][512];   // 64 KiB
    __shared__ float red[8];

    const float4* og4 = (const float4*)(OG + (size_t)b * H_DIM);
    float4 o = og4[t];
    ogs[t] = o;
    float p = dot4(o, o);
    #pragma unroll
    for (int m = 32; m >= 1; m >>= 1) p += __shfl_xor(p, m, 64);
    if (lane == 0) red[wave] = p;
    __syncthreads();
    float og2 = 0.f;
    #pragma unroll
    for (int w = 0; w < 8; ++w) og2 += red[w];
    const float onorm = sqrtf(og2);

    const float4* e4a = (const float4*)(E + ((size_t)wave * B_DIM + b) * H_DIM);
    const float4* e4b = (const float4*)(E + ((size_t)(wave + 8) * B_DIM + b) * H_DIM);
    float4 ea[8], eb[8];
    #pragma unroll
    for (int i = 0; i < 8; ++i) {
        ea[i] = e4a[i * 64 + lane];
        eb[i] = e4b[i * 64 + lane];
    }
    float da = 0.f, na = 0.f, db = 0.f, nb = 0.f;
    #pragma unroll
    for (int i = 0; i < 8; ++i) {
        float4 og = ogs[i * 64 + lane];
        da += dot4(ea[i], og);
        na += dot4(ea[i], ea[i]);
        db += dot4(eb[i], og);
        nb += dot4(eb[i], eb[i]);
    }
    #pragma unroll
    for (int m = 32; m >= 1; m >>= 1) {
        da += __shfl_xor(da, m, 64);
        na += __shfl_xor(na, m, 64);
        db += __shfl_xor(db, m, 64);
        nb += __shfl_xor(nb, m, 64);
    }
    const float sima = da / fmaxf(sqrtf(na) * onorm, EPS);
    const float simb = db / fmaxf(sqrtf(nb) * onorm, EPS);

    #pragma unroll
    for (int i = 0; i < 8; ++i) {
        float4 v;
        v.x = ea[i].x * sima + eb[i].x * simb;
        v.y = ea[i].y * sima + eb[i].y * simb;
        v.z = ea[i].z * sima + eb[i].z * simb;
        v.w = ea[i].w * sima + eb[i].w * simb;
        buf[wave][i * 64 + lane] = v;
    }
    __syncthreads();

    float4 s = buf[0][t];
    #pragma unroll
    for (int w = 1; w < 8; ++w) {
        float4 v = buf[w][t];
        s.x += v.x; s.y += v.y; s.z += v.z; s.w += v.w;
    }
    const float sc = 1.f / (float)S_DIM;
    // Fragment-order store: thread t holds h = 4t..4t+3 of row b.
    {
        const int ki = t >> 3;            // h>>5
        const int quad = (t >> 1) & 3;    // (h>>3)&3
        const int j0 = (t & 1) * 4;       // h&7 rounded to 4
        const int l = (b & 15) | (quad << 4);
        const size_t off = ((size_t)((b >> 4) * KT + ki)) * 512 + l * 8 + j0;
        ushort4 ob;
        ob.x = f2bf(s.x * sc); ob.y = f2bf(s.y * sc);
        ob.z = f2bf(s.z * sc); ob.w = f2bf(s.w * sc);
        *(ushort4*)(wrep_sw + off) = ob;
    }

    // Fused W -> bf16 tail in fragment order: block b converts rows n = 4b..4b+3.
    const float4* w4 = (const float4*)W;
    #pragma unroll
    for (int j = 0; j < 4; ++j) {
        const int n = b * 4 + j;
        const size_t idx = (size_t)n * 512 + t;   // float4 index into W row n
        float4 v = w4[idx];
        const int ki = t >> 3;
        const int quad = (t >> 1) & 3;
        const int j0 = (t & 1) * 4;
        const int l = (n & 15) | (quad << 4);
        const size_t off = ((size_t)((n >> 4) * KT + ki)) * 512 + l * 8 + j0;
        ushort4 c;
        c.x = f2bf(v.x); c.y = f2bf(v.y); c.z = f2bf(v.z); c.w = f2bf(v.w);
        *(ushort4*)(Wb_sw + off) = c;
    }
}

// ---------------- Kernel 2: fragment-direct GEMM, no LDS, no barriers ----------------
// grid (32, 8), 256 thr. Wave w: mi0 = by*4 + (w&1)*2, ni0 = bx*4 + (w>>1)*2.
// Each wave: 32x32 output via 2x2 accs; per K32: 4 coalesced dwordx4 frag loads
// (base + lane*16) + 4 MFMAs. Ping-pong register prefetch; streams are 64 KiB
// contiguous per tile-row -> L2-friendly; paired waves share streams (L1 hits).
__global__ __launch_bounds__(256) void gemm_kernel(
    const unsigned short* __restrict__ A, const unsigned short* __restrict__ Bw,
    const float* __restrict__ bias, float* __restrict__ out) {
    const int t = threadIdx.x;
    const int lane = t & 63;
    const int wave = t >> 6;
    const int mi0 = blockIdx.y * 4 + (wave & 1) * 2;
    const int ni0 = blockIdx.x * 4 + (wave >> 1) * 2;

    const bf16x8* Af = (const bf16x8*)A;
    const bf16x8* Bf = (const bf16x8*)Bw;
    // bf16x8 index of tile (i, ki), lane l: i*64*64 + ki*64 + l
    const int a0b = mi0 * (KT * 64) + lane;
    const int a1b = (mi0 + 1) * (KT * 64) + lane;
    const int b0b = ni0 * (KT * 64) + lane;
    const int b1b = (ni0 + 1) * (KT * 64) + lane;

    f32x4 acc00 = {0.f, 0.f, 0.f, 0.f};
    f32x4 acc01 = {0.f, 0.f, 0.f, 0.f};
    f32x4 acc10 = {0.f, 0.f, 0.f, 0.f};
    f32x4 acc11 = {0.f, 0.f, 0.f, 0.f};

    bf16x8 a0c = Af[a0b], a1c = Af[a1b];
    bf16x8 b0c = Bf[b0b], b1c = Bf[b1b];

    for (int ki = 0; ki < KT - 1; ++ki) {
        const int nx = (ki + 1) * 64;
        bf16x8 a0n = Af[a0b + nx];
        bf16x8 a1n = Af[a1b + nx];
        bf16x8 b0n = Bf[b0b + nx];
        bf16x8 b1n = Bf[b1b + nx];
        acc00 = __builtin_amdgcn_mfma_f32_16x16x32_bf16(a0c, b0c, acc00, 0, 0, 0);
        acc01 = __builtin_amdgcn_mfma_f32_16x16x32_bf16(a0c, b1c, acc01, 0, 0, 0);
        acc10 = __builtin_amdgcn_mfma_f32_16x16x32_bf16(a1c, b0c, acc10, 0, 0, 0);
        acc11 = __builtin_amdgcn_mfma_f32_16x16x32_bf16(a1c, b1c, acc11, 0, 0, 0);
        a0c = a0n; a1c = a1n; b0c = b0n; b1c = b1n;
    }
    acc00 = __builtin_amdgcn_mfma_f32_16x16x32_bf16(a0c, b0c, acc00, 0, 0, 0);
    acc01 = __builtin_amdgcn_mfma_f32_16x16x32_bf16(a0c, b1c, acc01, 0, 0, 0);
    acc10 = __builtin_amdgcn_mfma_f32_16x16x32_bf16(a1c, b0c, acc10, 0, 0, 0);
    acc11 = __builtin_amdgcn_mfma_f32_16x16x32_bf16(a1c, b1c, acc11, 0, 0, 0);

    // D mapping: col=lane&15, row=(lane>>4)*4+reg
    const int col = lane & 15;
    const int q = lane >> 4;
    const int m0 = mi0 * 16;
    const int n0 = ni0 * 16;
    const float bias0 = bias[n0 + col];
    const float bias1 = bias[n0 + 16 + col];
    #pragma unroll
    for (int r = 0; r < 4; ++r) {
        const int mr = q * 4 + r;
        float* o0 = out + (size_t)(m0 + mr) * H_DIM + n0;
        float* o1 = out + (size_t)(m0 + 16 + mr) * H_DIM + n0;
        o0[col]      = acc00[r] + bias0;
        o0[16 + col] = acc01[r] + bias1;
        o1[col]      = acc10[r] + bias0;
        o1[16 + col] = acc11[r] + bias1;
    }
}

extern "C" void kernel_launch(void* const* d_in, const int* in_sizes, int n_in,
                              void* d_out, int out_size, void* d_ws, size_t ws_size,
                              hipStream_t stream) {
    const float* OG   = (const float*)d_in[0];
    const float* E    = (const float*)d_in[1];
    const float* W    = (const float*)d_in[2];
    const float* bias = (const float*)d_in[3];
    float* out = (float*)d_out;

    unsigned short* wrep_sw = (unsigned short*)d_ws;                  // 2 MiB, fragment order
    unsigned short* Wb_sw   = wrep_sw + (size_t)B_DIM * H_DIM;        // 8 MiB, fragment order

    simwrep_kernel<<<B_DIM, 512, 0, stream>>>(OG, E, W, wrep_sw, Wb_sw);
    gemm_kernel<<<dim3(H_DIM / 64, B_DIM / 64), 256, 0, stream>>>(wrep_sw, Wb_sw, bias, out);
}

// Round 7
// 127.285 us; speedup vs baseline: 1.0200x; 1.0200x over previous
//
#include <hip/hip_runtime.h>

#define S_DIM 16
#define B_DIM 512
#define H_DIM 2048
#define EPS 1e-8f

typedef short bf16x8 __attribute__((ext_vector_type(8)));
typedef float f32x4 __attribute__((ext_vector_type(4)));

__device__ __forceinline__ unsigned short f2bf(float f) {
    union { float f; unsigned int u; } v; v.f = f;
    unsigned int u = v.u;
    unsigned int r = (u + 0x7fffu + ((u >> 16) & 1u)) >> 16;
    return (unsigned short)r;
}

__device__ __forceinline__ float dot4(const float4& a, const float4& b) {
    return a.x*b.x + a.y*b.y + a.z*b.z + a.w*b.w;
}

// async 16B global->LDS DMA. LDS side writes wave-uniform base + lane*16.
__device__ __forceinline__ void gld16(const void* g, void* l) {
    __builtin_amdgcn_global_load_lds(
        (const __attribute__((address_space(1))) unsigned int*)g,
        (__attribute__((address_space(3))) unsigned int*)l, 16, 0, 0);
}

// ---------------- Kernel 1: sims + weighted mean -> wRep (bf16), fused W->bf16 ----------------
// (byte-identical to R5 best: dual-row per wave, OG in LDS, E read once, W tail)
__global__ __launch_bounds__(512, 4) void simwrep_kernel(
    const float* __restrict__ OG, const float* __restrict__ E,
    const float* __restrict__ W, unsigned short* __restrict__ wrep,
    unsigned short* __restrict__ Wb) {
    const int b = blockIdx.x;
    const int t = threadIdx.x;
    const int lane = t & 63;
    const int wave = t >> 6;

    __shared__ float4 ogs[512];      // 8 KiB
    __shared__ float4 buf[8][512];   // 64 KiB
    __shared__ float red[8];

    const float4* og4 = (const float4*)(OG + (size_t)b * H_DIM);
    float4 o = og4[t];
    ogs[t] = o;
    float p = dot4(o, o);
    #pragma unroll
    for (int m = 32; m >= 1; m >>= 1) p += __shfl_xor(p, m, 64);
    if (lane == 0) red[wave] = p;
    __syncthreads();
    float og2 = 0.f;
    #pragma unroll
    for (int w = 0; w < 8; ++w) og2 += red[w];
    const float onorm = sqrtf(og2);

    const float4* e4a = (const float4*)(E + ((size_t)wave * B_DIM + b) * H_DIM);
    const float4* e4b = (const float4*)(E + ((size_t)(wave + 8) * B_DIM + b) * H_DIM);
    float4 ea[8], eb[8];
    #pragma unroll
    for (int i = 0; i < 8; ++i) {
        ea[i] = e4a[i * 64 + lane];
        eb[i] = e4b[i * 64 + lane];
    }
    float da = 0.f, na = 0.f, db = 0.f, nb = 0.f;
    #pragma unroll
    for (int i = 0; i < 8; ++i) {
        float4 og = ogs[i * 64 + lane];
        da += dot4(ea[i], og);
        na += dot4(ea[i], ea[i]);
        db += dot4(eb[i], og);
        nb += dot4(eb[i], eb[i]);
    }
    #pragma unroll
    for (int m = 32; m >= 1; m >>= 1) {
        da += __shfl_xor(da, m, 64);
        na += __shfl_xor(na, m, 64);
        db += __shfl_xor(db, m, 64);
        nb += __shfl_xor(nb, m, 64);
    }
    const float sima = da / fmaxf(sqrtf(na) * onorm, EPS);
    const float simb = db / fmaxf(sqrtf(nb) * onorm, EPS);

    #pragma unroll
    for (int i = 0; i < 8; ++i) {
        float4 v;
        v.x = ea[i].x * sima + eb[i].x * simb;
        v.y = ea[i].y * sima + eb[i].y * simb;
        v.z = ea[i].z * sima + eb[i].z * simb;
        v.w = ea[i].w * sima + eb[i].w * simb;
        buf[wave][i * 64 + lane] = v;
    }
    __syncthreads();

    float4 s = buf[0][t];
    #pragma unroll
    for (int w = 1; w < 8; ++w) {
        float4 v = buf[w][t];
        s.x += v.x; s.y += v.y; s.z += v.z; s.w += v.w;
    }
    const float sc = 1.f / (float)S_DIM;
    ushort4 ob;
    ob.x = f2bf(s.x * sc); ob.y = f2bf(s.y * sc);
    ob.z = f2bf(s.z * sc); ob.w = f2bf(s.w * sc);
    ((ushort4*)wrep)[(size_t)b * (H_DIM / 4) + t] = ob;

    const float4* w4 = (const float4*)W;
    #pragma unroll
    for (int j = 0; j < 4; ++j) {
        const size_t idx = (size_t)b * 2048 + j * 512 + t;
        float4 v = w4[idx];
        ushort4 c;
        c.x = f2bf(v.x); c.y = f2bf(v.y); c.z = f2bf(v.z); c.w = f2bf(v.w);
        ((ushort4*)Wb)[idx] = c;
    }
}

// ---------------- Kernel 2: out = wRep @ Wb^T + b  (bf16 MFMA, fp32 acc) ----------------
// 64(M)x32(N) tiles, BK=64, 512 blocks (2/CU), 4 waves each 32x16 output.
// Staging via global_load_lds width=16 (async DMA, no VGPR round-trip).
// LDS rows are 64 shorts, UNPADDED; bank conflicts broken by XOR-swizzling the
// 8-short k-group: stored (row, c8) holds global group c8 ^ (row&7). The swizzle
// is applied on the global SOURCE address per lane (source stays row-major).
__global__ __launch_bounds__(256) void gemm_kernel(
    const unsigned short* __restrict__ A, const unsigned short* __restrict__ Wb,
    const float* __restrict__ bias, float* __restrict__ out) {
    const int n0 = blockIdx.x * 32;
    const int m0 = blockIdx.y * 64;

    __shared__ __align__(16) unsigned short As[64 * 64];  // 8 KiB
    __shared__ __align__(16) unsigned short Ws[32 * 64];  // 4 KiB

    const int t = threadIdx.x;
    const int lane = t & 63;
    const int wave = t >> 6;
    const int wm = (wave & 1) * 32;
    const int wn = (wave >> 1) * 16;

    // staging: wave w fills As rows 16w..16w+15 (two 1 KiB chunks) and
    // Ws rows 8w..8w+7 (one 1 KiB chunk). lane l -> row base + (l>>3), c8 = l&7.
    const int lrow = lane >> 3;
    const int lc8  = lane & 7;
    const int arow0 = wave * 16 + lrow;
    const int arow1 = wave * 16 + 8 + lrow;
    const int brow  = wave * 8 + lrow;
    const unsigned short* agp0 = A  + (size_t)(m0 + arow0) * H_DIM + (lc8 ^ (arow0 & 7)) * 8;
    const unsigned short* agp1 = A  + (size_t)(m0 + arow1) * H_DIM + (lc8 ^ (arow1 & 7)) * 8;
    const unsigned short* bgp  = Wb + (size_t)(n0 + brow ) * H_DIM + (lc8 ^ (brow  & 7)) * 8;
    unsigned short* alp0 = As + wave * 1024;        // wave-uniform LDS bases
    unsigned short* alp1 = As + wave * 1024 + 512;
    unsigned short* blp  = Ws + wave * 512;

    f32x4 acc0 = {0.f, 0.f, 0.f, 0.f};
    f32x4 acc1 = {0.f, 0.f, 0.f, 0.f};

    const int row = lane & 15;
    const int q = lane >> 4;
    const int rm0 = (wm + row) * 64;
    const int rm1 = (wm + 16 + row) * 64;
    const int rb0 = (wn + row) * 64;
    const int rx = row & 7;   // swizzle key (wm/wn are multiples of 8)

    for (int k0 = 0; k0 < H_DIM; k0 += 64) {
        gld16(agp0, alp0);
        gld16(agp1, alp1);
        gld16(bgp,  blp);
        agp0 += 64; agp1 += 64; bgp += 64;
        __syncthreads();                       // drain DMA, publish tile
        #pragma unroll
        for (int ks = 0; ks < 2; ++ks) {
            const int sx = ((ks * 4 + q) ^ rx) * 8;
            bf16x8 a0 = *(const bf16x8*)&As[rm0 + sx];
            bf16x8 a1 = *(const bf16x8*)&As[rm1 + sx];
            bf16x8 b0 = *(const bf16x8*)&Ws[rb0 + sx];
            acc0 = __builtin_amdgcn_mfma_f32_16x16x32_bf16(a0, b0, acc0, 0, 0, 0);
            acc1 = __builtin_amdgcn_mfma_f32_16x16x32_bf16(a1, b0, acc1, 0, 0, 0);
        }
        __syncthreads();                       // reads done before next overwrite
    }

    // D mapping: col=lane&15, row=(lane>>4)*4+reg
    const int col = lane & 15;
    const float bias0 = bias[n0 + wn + col];
    #pragma unroll
    for (int r = 0; r < 4; ++r) {
        const int mr = q * 4 + r;
        float* o0 = out + (size_t)(m0 + wm + mr) * H_DIM + n0 + wn;
        float* o1 = out + (size_t)(m0 + wm + 16 + mr) * H_DIM + n0 + wn;
        o0[col] = acc0[r] + bias0;
        o1[col] = acc1[r] + bias0;
    }
}

extern "C" void kernel_launch(void* const* d_in, const int* in_sizes, int n_in,
                              void* d_out, int out_size, void* d_ws, size_t ws_size,
                              hipStream_t stream) {
    const float* OG   = (const float*)d_in[0];
    const float* E    = (const float*)d_in[1];
    const float* W    = (const float*)d_in[2];
    const float* bias = (const float*)d_in[3];
    float* out = (float*)d_out;

    unsigned short* wrep = (unsigned short*)d_ws;                 // 2 MiB bf16
    unsigned short* Wb   = wrep + (size_t)B_DIM * H_DIM;          // 8 MiB bf16

    simwrep_kernel<<<B_DIM, 512, 0, stream>>>(OG, E, W, wrep, Wb);
    gemm_kernel<<<dim3(H_DIM / 32, B_DIM / 64), 256, 0, stream>>>(wrep, Wb, bias, out);
}